// Round 17
// baseline (2053.708 us; speedup 1.0000x reference)
//
#include <hip/hip_runtime.h>

#define DIM 384
#define PATCHES 196
#define HID 1536
#define NBLK 24
#define NPAD 256                    // K-padded patch count for attn GEMM (fp8 bytes)
#define XROWS (64 * PATCHES)        // 12544
#define BDCOLS (64 * DIM)           // 24576
#define XELEMS (XROWS * DIM)        // 4816896
#define ESTRIDE 132                 // epilogue LDS stage row stride (floats)

typedef __attribute__((ext_vector_type(8))) short s8v;
typedef __attribute__((ext_vector_type(4))) float f4v;
typedef __attribute__((ext_vector_type(4))) int i32x4;
typedef __attribute__((ext_vector_type(8))) int i32x8;
typedef unsigned char uchar;

__device__ __forceinline__ short f2bf(float f) {
  unsigned u = __float_as_uint(f);
  u += 0x7FFFu + ((u >> 16) & 1u);   // RNE f32 -> bf16
  return (short)(u >> 16);
}

__device__ __forceinline__ float gelu_f(float x) {
  float u2 = 1.5957691216f * (x + 0.044715f * x * x * x);
  return x / (1.0f + __expf(-u2));
}

__device__ __forceinline__ unsigned pk4_fp8(float a, float b, float c, float d) {
  int lo = __builtin_amdgcn_cvt_pk_fp8_f32(a, b, 0, false);
  int full = __builtin_amdgcn_cvt_pk_fp8_f32(c, d, lo, true);
  return (unsigned)full;
}
__device__ __forceinline__ uchar fp8_1(float a) {
  return (uchar)(__builtin_amdgcn_cvt_pk_fp8_f32(a, a, 0, false) & 0xff);
}

__device__ __forceinline__ void gload_lds16(const void* g, void* l) {
  __builtin_amdgcn_global_load_lds((const __attribute__((address_space(1))) void*)g,
                                   (__attribute__((address_space(3))) void*)l, 16, 0, 0);
}

// ---------------- absmax (per-tensor, float4) ----------------
__global__ __launch_bounds__(256)
void absmax_v4(const float* __restrict__ src, int f4per, int blocks_per,
               unsigned* __restrict__ out) {
  int tens = blockIdx.x / blocks_per;
  int sl = blockIdx.x - tens * blocks_per;
  const float4* p = (const float4*)(src + (size_t)tens * f4per * 4);
  float m = 0.f;
  for (int i = sl * 256 + threadIdx.x; i < f4per; i += blocks_per * 256) {
    float4 v = p[i];
    m = fmaxf(m, fmaxf(fmaxf(fabsf(v.x), fabsf(v.y)), fmaxf(fabsf(v.z), fabsf(v.w))));
  }
  __shared__ float red[256];
  red[threadIdx.x] = m;
  __syncthreads();
  for (int s = 128; s > 0; s >>= 1) {
    if ((int)threadIdx.x < s) red[threadIdx.x] = fmaxf(red[threadIdx.x], red[threadIdx.x + s]);
    __syncthreads();
  }
  if (threadIdx.x == 0) atomicMax(out + tens, __float_as_uint(red[0]));
}

// ---------------- quantize conv weights (fq bit-exact, bf16 store) ----------------
__global__ __launch_bounds__(256)
void quant_w(const float* __restrict__ w, short* __restrict__ q,
             const unsigned* __restrict__ sc, int per, int total) {
  int i = blockIdx.x * 256 + threadIdx.x;
  if (i >= total) return;
  int tens = i / per;
  float s = __uint_as_float(sc[tens]) / 127.0f + 1e-8f;
  float v = rintf(w[i] / s);
  v = fminf(fmaxf(v, -128.0f), 127.0f) * s;
  q[i] = f2bf(v);
}

// ---------------- quantize mlp weights (fq then fp8 e4m3, x4 vector) ----------------
__global__ __launch_bounds__(256)
void quant_fp8(const float* __restrict__ w, unsigned* __restrict__ q,
               const unsigned* __restrict__ sc, int per, int total4) {
  int i = blockIdx.x * 256 + threadIdx.x;
  if (i >= total4) return;
  int e = i << 2;
  int tens = e / per;
  float s = __uint_as_float(sc[tens]) / 127.0f + 1e-8f;
  float4 w4 = *(const float4*)(w + e);
  float a = fminf(fmaxf(rintf(w4.x / s), -128.0f), 127.0f) * s;
  float b = fminf(fmaxf(rintf(w4.y / s), -128.0f), 127.0f) * s;
  float c = fminf(fmaxf(rintf(w4.z / s), -128.0f), 127.0f) * s;
  float d = fminf(fmaxf(rintf(w4.w / s), -128.0f), 127.0f) * s;
  q[i] = pk4_fp8(a, b, c, d);
}

__global__ __launch_bounds__(256)
void quant_attn_fp8(const float* __restrict__ w, unsigned* __restrict__ q,
                    const unsigned* __restrict__ sc) {
  int i = blockIdx.x * 256 + threadIdx.x;       // over 24*196*256/4
  if (i >= NBLK * PATCHES * NPAD / 4) return;
  int e = i << 2;
  int col = e & (NPAD - 1);
  int rt = e >> 8;
  int row = rt % PATCHES;
  int tens = rt / PATCHES;
  float s = __uint_as_float(sc[tens]) / 127.0f + 1e-8f;
  const float* wr = w + (size_t)tens * PATCHES * PATCHES + (size_t)row * PATCHES;
  float v[4];
#pragma unroll
  for (int k = 0; k < 4; ++k) {
    int c = col + k;
    v[k] = (c < PATCHES) ? fminf(fmaxf(rintf(wr[c] / s), -128.0f), 127.0f) * s : 0.f;
  }
  q[i] = pk4_fp8(v[0], v[1], v[2], v[3]);
}

__global__ __launch_bounds__(256)
void quant_head_v4(const float* __restrict__ w, float* __restrict__ q,
                   const unsigned* __restrict__ sc) {
  int i = blockIdx.x * 256 + threadIdx.x;
  if (i >= 1000 * DIM / 4) return;
  float s = __uint_as_float(sc[0]) / 127.0f + 1e-8f;
  float4 w4 = *(const float4*)(w + (i << 2));
  float4 o;
  o.x = fminf(fmaxf(rintf(w4.x / s), -128.0f), 127.0f) * s;
  o.y = fminf(fmaxf(rintf(w4.y / s), -128.0f), 127.0f) * s;
  o.z = fminf(fmaxf(rintf(w4.z / s), -128.0f), 127.0f) * s;
  o.w = fminf(fmaxf(rintf(w4.w / s), -128.0f), 127.0f) * s;
  *(float4*)(q + (i << 2)) = o;
}

// ---------------- im2col + bf16 cast (stride-16 16x16 patches: no overlap) ----------------
__global__ __launch_bounds__(256)
void im2col_k(const float* __restrict__ x, short* __restrict__ Xa) {
  int idx = blockIdx.x * 256 + threadIdx.x;     // each handles 4 elems
  if (idx >= XROWS * 768 / 4) return;
  int e = idx << 2;
  int r = e / 768, k = e - r * 768;
  int b = r / PATCHES, p = r - b * PATCHES;
  int c = k >> 8, rem = k & 255, ii = rem >> 4, j = rem & 15;
  int ph = p / 14, pw = p - ph * 14;
  const float4 v = *(const float4*)(x + (b * 3 + c) * 50176 + (ph * 16 + ii) * 224 + pw * 16 + j);
  short2* o = (short2*)(Xa + e);
  o[0] = make_short2(f2bf(v.x), f2bf(v.y));
  o[1] = make_short2(f2bf(v.z), f2bf(v.w));
}

// ---------------- conv GEMM (bf16): X = Xa * Wc^T + b; fused norm1 -> Yt (fp8) ------
__global__ __launch_bounds__(256)
void gemm_conv(const short* __restrict__ A, const short* __restrict__ B,
               float* __restrict__ Xres, const float* __restrict__ bias,
               const float* __restrict__ n1a, const float* __restrict__ n1b,
               uchar* __restrict__ Yt) {
  constexpr int TILE_SHORTS = 192 * 64;
  __shared__ char smem[2 * TILE_SHORTS * 2];     // 49152 B
  short* buf0 = (short*)smem;
  float* S = (float*)smem;
  const int lda = 768, K = 768;

  const int t = threadIdx.x;
  const int lane = t & 63;
  const int wid = t >> 6;
  const int wr = wid >> 1, wc = wid & 1;

  const int gx = gridDim.x;
  const int nwg = gx * gridDim.y;
  const int orig = blockIdx.y * gx + blockIdx.x;
  const int q = nwg >> 3, rm = nwg & 7;
  const int xc = orig & 7, jj = orig >> 3;
  const int wg = (xc < rm ? xc * (q + 1) : rm * (q + 1) + (xc - rm) * q) + jj;
  const int bx = wg % gx, by = wg / gx;
  const int m0 = by * 64, n0 = bx * 128;

  f4v acc[2][4];
#pragma unroll
  for (int m = 0; m < 2; ++m)
#pragma unroll
    for (int n = 0; n < 4; ++n) acc[m][n] = (f4v){0.f, 0.f, 0.f, 0.f};

  const int srow = t >> 3;
  const int scol = ((t & 7) ^ (srow & 7)) << 3;  // shorts
  const short* ga[2];
#pragma unroll
  for (int h = 0; h < 2; ++h) ga[h] = A + (size_t)(m0 + h * 32 + srow) * lda + scol;
  const short* gb[4];
#pragma unroll
  for (int j = 0; j < 4; ++j) gb[j] = B + (size_t)(n0 + j * 32 + srow) * lda + scol;
  short* ldst = buf0 + (t & ~63) * 8;

  auto stage = [&](int slot, int kt) {
    const int koff = kt << 6;
    const int boff = slot * TILE_SHORTS;
    gload_lds16(ga[0] + koff, ldst + boff);
    gload_lds16(ga[1] + koff, ldst + boff + 2048);
#pragma unroll
    for (int j = 0; j < 4; ++j)
      gload_lds16(gb[j] + koff, ldst + boff + 4096 + j * 2048);
  };

  const int l15 = lane & 15, lk = lane >> 4, l7 = lane & 7;
  int paoff[2], pboff[2];
#pragma unroll
  for (int ks = 0; ks < 2; ++ks) {
    const int cgx = ((ks << 2) + lk) ^ l7;
    paoff[ks] = (wr * 32 + l15) * 64 + (cgx << 3);
    pboff[ks] = 4096 + (wc * 64 + l15) * 64 + (cgx << 3);
  }

  const int nk = K >> 6;
  stage(0, 0);
  asm volatile("s_waitcnt vmcnt(0)" ::: "memory");
  __builtin_amdgcn_s_barrier();
  for (int kt = 0; kt < nk; ++kt) {
    const int cur = kt & 1;
    if (kt + 1 < nk) stage(cur ^ 1, kt + 1);
    const short* base = buf0 + cur * TILE_SHORTS;
    s8v af[2][2], bfr[4][2];
#pragma unroll
    for (int m = 0; m < 2; ++m)
#pragma unroll
      for (int ks = 0; ks < 2; ++ks) af[m][ks] = *(const s8v*)(base + paoff[ks] + m * 1024);
#pragma unroll
    for (int n = 0; n < 4; ++n)
#pragma unroll
      for (int ks = 0; ks < 2; ++ks) bfr[n][ks] = *(const s8v*)(base + pboff[ks] + n * 1024);
    asm volatile("s_waitcnt lgkmcnt(0)" ::: "memory");
    __builtin_amdgcn_sched_barrier(0);
    __builtin_amdgcn_s_setprio(1);
#pragma unroll
    for (int m = 0; m < 2; ++m)
#pragma unroll
      for (int n = 0; n < 4; ++n)
#pragma unroll
        for (int ks = 0; ks < 2; ++ks)
          acc[m][n] = __builtin_amdgcn_mfma_f32_16x16x32_bf16(af[m][ks], bfr[n][ks], acc[m][n], 0, 0, 0);
    __builtin_amdgcn_s_setprio(0);
    if (kt + 1 < nk) {
      asm volatile("s_waitcnt vmcnt(0)" ::: "memory");
      __builtin_amdgcn_s_barrier();
    }
  }

  // epilogue via LDS transpose
  const int cb = (wc << 6) + l15;
  const int rl = t >> 3;
  const int c0 = (t & 7) << 4;
#pragma unroll
  for (int m = 0; m < 2; ++m) {
    __syncthreads();
#pragma unroll
    for (int n = 0; n < 4; ++n) {
      int c = cb + n * 16;
#pragma unroll
      for (int j = 0; j < 4; ++j)
        S[((wr << 4) + (lk << 2) + j) * ESTRIDE + c] = acc[m][n][j];
    }
    __syncthreads();
    const int r = m0 + (rl >> 4) * 32 + m * 16 + (rl & 15);
    const int colg = n0 + c0;
    float xn[16];
#pragma unroll
    for (int i = 0; i < 4; ++i) {
      float4 q4 = *(const float4*)(S + rl * ESTRIDE + c0 + i * 4);
      float4 b4 = *(const float4*)(bias + colg + i * 4);
      float4 o4 = make_float4(q4.x + b4.x, q4.y + b4.y, q4.z + b4.z, q4.w + b4.w);
      *(float4*)(Xres + (size_t)r * DIM + colg + i * 4) = o4;
      xn[4 * i] = o4.x; xn[4 * i + 1] = o4.y; xn[4 * i + 2] = o4.z; xn[4 * i + 3] = o4.w;
    }
    int bb = r / PATCHES, p = r - bb * PATCHES;
    uchar* yrow = Yt + ((size_t)(bb * DIM + colg)) * NPAD + p;
#pragma unroll
    for (int i = 0; i < 4; ++i) {
      float4 a4 = *(const float4*)(n1a + colg + i * 4);
      float4 b4 = *(const float4*)(n1b + colg + i * 4);
      yrow[(4 * i + 0) * NPAD] = fp8_1(xn[4 * i] * a4.x + b4.x);
      yrow[(4 * i + 1) * NPAD] = fp8_1(xn[4 * i + 1] * a4.y + b4.y);
      yrow[(4 * i + 2) * NPAD] = fp8_1(xn[4 * i + 2] * a4.z + b4.z);
      yrow[(4 * i + 3) * NPAD] = fp8_1(xn[4 * i + 3] * a4.w + b4.w);
    }
  }
}

// ---------------- FP8 GEMM C = A * B^T, tile 64x128, BK=128, MX MFMA ---------------
// MX path: one mfma_scale_f32_16x16x128_f8f6f4 (unit E8M0 scales = 0x7F) per K-step
// per (m,n). T4 3-buffer pipeline: 2 tiles in flight, steady-state vmcnt(6) -- next
// tile's 6 loads get a full compute period + issue window to land (never drain to 0
// mid-loop). Slot (kt+2)%3 was last read two barriers ago -> safe to overwrite.
// EPI 1: attn -> xn = X + g1*(acc + bias[r]); X = xn; Y2fp8 = xn*n2a+n2b
// EPI 2: mlp1 -> H = fp8(gelu(acc + bias[c]))
// EPI 3: mlp2 -> X += g2*(acc + bias[c]); fused norm1 -> Yt fp8 (next layer)
template <int EPI>
__global__ __launch_bounds__(256)
void gemm8(const uchar* __restrict__ A, int lda8, int Mlim,
           const uchar* __restrict__ B, int ldb8, int K,
           float* __restrict__ Xres, uchar* __restrict__ OutB8,
           const float* __restrict__ bias, const float* __restrict__ gamma,
           const float* __restrict__ n2a, const float* __restrict__ n2b,
           const float* __restrict__ n1a, const float* __restrict__ n1b,
           uchar* __restrict__ Yt) {
  constexpr int TILE_BYTES = 192 * 128;          // A 64x128B + B 128x128B = 24576
  __shared__ char smem[3 * TILE_BYTES];          // 73728 B -> 2 blocks/CU (same as 2-buf measured)
  char* buf0 = smem;
  float* S = (float*)smem;

  const int t = threadIdx.x;
  const int lane = t & 63;
  const int wid = t >> 6;
  const int wr = wid >> 1, wc = wid & 1;

  const int gx = gridDim.x;
  const int nwg = gx * gridDim.y;
  const int orig = blockIdx.y * gx + blockIdx.x;
  const int q = nwg >> 3, rm = nwg & 7;
  const int xc = orig & 7, jj = orig >> 3;
  const int wg = (xc < rm ? xc * (q + 1) : rm * (q + 1) + (xc - rm) * q) + jj;
  const int bx = wg % gx, by = wg / gx;
  const int m0 = by * 64, n0 = bx * 128;

  f4v acc[2][4];
#pragma unroll
  for (int m = 0; m < 2; ++m)
#pragma unroll
    for (int n = 0; n < 4; ++n) acc[m][n] = (f4v){0.f, 0.f, 0.f, 0.f};

  // staging: thread t -> (row = pass*32 + (t>>3), chunk_pos = t&7); src chunk pre-swizzled
  const int srow = t >> 3;
  const int scolB = (((t & 7) ^ (srow & 7)) << 4);   // bytes
  const uchar* ga[2];
#pragma unroll
  for (int h = 0; h < 2; ++h) {
    int r = m0 + h * 32 + srow;
    if (r >= Mlim) r = Mlim - 1;
    ga[h] = A + (size_t)r * lda8 + scolB;
  }
  const uchar* gb[4];
#pragma unroll
  for (int j = 0; j < 4; ++j)
    gb[j] = B + (size_t)(n0 + j * 32 + srow) * ldb8 + scolB;
  char* ldst = buf0 + (t & ~63) * 16;              // wave base; HW adds lane*16B

  auto stage = [&](int slot, int kt) {
    const int koff = kt << 7;                      // 128 B per K-tile
    const int boff = slot * TILE_BYTES;
    gload_lds16(ga[0] + koff, ldst + boff);
    gload_lds16(ga[1] + koff, ldst + boff + 4096);
#pragma unroll
    for (int j = 0; j < 4; ++j)
      gload_lds16(gb[j] + koff, ldst + boff + 8192 + j * 4096);
  };

  const int l15 = lane & 15, lk = lane >> 4, l7 = lane & 7;
  // MX fragment: two 16B chunks per operand, global chunks 2*lk, 2*lk+1
  const int cA0 = (((lk << 1) | 0) ^ l7) << 4;
  const int cA1 = (((lk << 1) | 1) ^ l7) << 4;
  int arow[2], brow[4];
#pragma unroll
  for (int m = 0; m < 2; ++m) arow[m] = (wr * 32 + m * 16 + l15) << 7;
#pragma unroll
  for (int n = 0; n < 4; ++n) brow[n] = 8192 + ((wc * 64 + n * 16 + l15) << 7);

  const int nk = K >> 7;
  stage(0, 0);
  if (nk > 1) stage(1, 1);
  asm volatile("s_waitcnt vmcnt(6)" ::: "memory");   // tile0 landed; tile1 may fly
  __builtin_amdgcn_s_barrier();
  int rb = 0;                                        // read slot
  for (int kt = 0; kt < nk; ++kt) {
    if (kt + 2 < nk) {
      int sb = rb + 2; if (sb >= 3) sb -= 3;
      stage(sb, kt + 2);                             // in flight: tiles kt+1, kt+2
    }
    const char* base = buf0 + rb * TILE_BYTES;
    i32x8 af[2], bfr[4];
#pragma unroll
    for (int m = 0; m < 2; ++m) {
      i32x4 lo = *(const i32x4*)(base + arow[m] + cA0);
      i32x4 hi = *(const i32x4*)(base + arow[m] + cA1);
      af[m][0] = lo[0]; af[m][1] = lo[1]; af[m][2] = lo[2]; af[m][3] = lo[3];
      af[m][4] = hi[0]; af[m][5] = hi[1]; af[m][6] = hi[2]; af[m][7] = hi[3];
    }
#pragma unroll
    for (int n = 0; n < 4; ++n) {
      i32x4 lo = *(const i32x4*)(base + brow[n] + cA0);
      i32x4 hi = *(const i32x4*)(base + brow[n] + cA1);
      bfr[n][0] = lo[0]; bfr[n][1] = lo[1]; bfr[n][2] = lo[2]; bfr[n][3] = lo[3];
      bfr[n][4] = hi[0]; bfr[n][5] = hi[1]; bfr[n][6] = hi[2]; bfr[n][7] = hi[3];
    }
    asm volatile("s_waitcnt lgkmcnt(0)" ::: "memory");
    __builtin_amdgcn_sched_barrier(0);
    __builtin_amdgcn_s_setprio(1);
#pragma unroll
    for (int m = 0; m < 2; ++m)
#pragma unroll
      for (int n = 0; n < 4; ++n)
        acc[m][n] = __builtin_amdgcn_mfma_scale_f32_16x16x128_f8f6f4(
            af[m], bfr[n], acc[m][n], 0, 0, 0, 0x7F7F7F7F, 0, 0x7F7F7F7F);
    __builtin_amdgcn_s_setprio(0);
    if (kt + 1 < nk) {
      if (kt + 2 < nk) { asm volatile("s_waitcnt vmcnt(6)" ::: "memory"); }  // tile kt+1 ready
      else            { asm volatile("s_waitcnt vmcnt(0)" ::: "memory"); }
      __builtin_amdgcn_s_barrier();
    }
    ++rb; if (rb >= 3) rb = 0;
  }

  // ---------------- epilogue via LDS transpose ----------------
  const int cb = (wc << 6) + l15;
  const int rl = t >> 3;
  const int c0 = (t & 7) << 4;
#pragma unroll
  for (int m = 0; m < 2; ++m) {
    __syncthreads();
#pragma unroll
    for (int n = 0; n < 4; ++n) {
      int c = cb + n * 16;
#pragma unroll
      for (int j = 0; j < 4; ++j)
        S[((wr << 4) + (lk << 2) + j) * ESTRIDE + c] = acc[m][n][j];
    }
    __syncthreads();
    const int r = m0 + (rl >> 4) * 32 + m * 16 + (rl & 15);
    const int colg = n0 + c0;
    float v[16];
#pragma unroll
    for (int i = 0; i < 4; ++i) {
      float4 q4 = *(const float4*)(S + rl * ESTRIDE + c0 + i * 4);
      v[4 * i] = q4.x; v[4 * i + 1] = q4.y; v[4 * i + 2] = q4.z; v[4 * i + 3] = q4.w;
    }
    if (EPI == 1) {
      if (r < Mlim) {
        const int b = colg / DIM, d0 = colg - b * DIM;
        const float br = bias[r];
        const size_t base2 = (size_t)b * (PATCHES * DIM) + (size_t)r * DIM + d0;
        float xn[16];
#pragma unroll
        for (int i = 0; i < 4; ++i) {
          float4 g4 = *(const float4*)(gamma + d0 + i * 4);
          float4 x4 = *(const float4*)(Xres + base2 + i * 4);
          x4.x += g4.x * (v[4 * i] + br);
          x4.y += g4.y * (v[4 * i + 1] + br);
          x4.z += g4.z * (v[4 * i + 2] + br);
          x4.w += g4.w * (v[4 * i + 3] + br);
          *(float4*)(Xres + base2 + i * 4) = x4;
          xn[4 * i] = x4.x; xn[4 * i + 1] = x4.y; xn[4 * i + 2] = x4.z; xn[4 * i + 3] = x4.w;
        }
        unsigned o[4];
#pragma unroll
        for (int i = 0; i < 4; ++i) {
          float4 a4 = *(const float4*)(n2a + d0 + i * 4);
          float4 b4 = *(const float4*)(n2b + d0 + i * 4);
          o[i] = pk4_fp8(xn[4 * i] * a4.x + b4.x, xn[4 * i + 1] * a4.y + b4.y,
                         xn[4 * i + 2] * a4.z + b4.z, xn[4 * i + 3] * a4.w + b4.w);
        }
        *(uint4*)(OutB8 + base2) = make_uint4(o[0], o[1], o[2], o[3]);
      }
    } else if (EPI == 2) {
      unsigned o[4];
#pragma unroll
      for (int i = 0; i < 4; ++i) {
        float g0 = gelu_f(v[4 * i] + bias[colg + 4 * i]);
        float g1 = gelu_f(v[4 * i + 1] + bias[colg + 4 * i + 1]);
        float g2 = gelu_f(v[4 * i + 2] + bias[colg + 4 * i + 2]);
        float g3 = gelu_f(v[4 * i + 3] + bias[colg + 4 * i + 3]);
        o[i] = pk4_fp8(g0, g1, g2, g3);
      }
      *(uint4*)(OutB8 + (size_t)r * HID + colg) = make_uint4(o[0], o[1], o[2], o[3]);
    } else {  // EPI == 3
      float xn[16];
#pragma unroll
      for (int i = 0; i < 4; ++i) {
        float4 b4 = *(const float4*)(bias + colg + i * 4);
        float4 g4 = *(const float4*)(gamma + colg + i * 4);
        float4 x4 = *(const float4*)(Xres + (size_t)r * DIM + colg + i * 4);
        x4.x += g4.x * (v[4 * i] + b4.x);
        x4.y += g4.y * (v[4 * i + 1] + b4.y);
        x4.z += g4.z * (v[4 * i + 2] + b4.z);
        x4.w += g4.w * (v[4 * i + 3] + b4.w);
        *(float4*)(Xres + (size_t)r * DIM + colg + i * 4) = x4;
        xn[4 * i] = x4.x; xn[4 * i + 1] = x4.y; xn[4 * i + 2] = x4.z; xn[4 * i + 3] = x4.w;
      }
      if (Yt != nullptr) {
        int bb = r / PATCHES, p = r - bb * PATCHES;
        uchar* yrow = Yt + ((size_t)(bb * DIM + colg)) * NPAD + p;
#pragma unroll
        for (int i = 0; i < 4; ++i) {
          float4 a4 = *(const float4*)(n1a + colg + i * 4);
          float4 b4 = *(const float4*)(n1b + colg + i * 4);
          yrow[(4 * i + 0) * NPAD] = fp8_1(xn[4 * i] * a4.x + b4.x);
          yrow[(4 * i + 1) * NPAD] = fp8_1(xn[4 * i + 1] * a4.y + b4.y);
          yrow[(4 * i + 2) * NPAD] = fp8_1(xn[4 * i + 2] * a4.z + b4.z);
          yrow[(4 * i + 3) * NPAD] = fp8_1(xn[4 * i + 3] * a4.w + b4.w);
        }
      }
    }
  }
}

// ---------------- final affine norm + mean pool (parallelized) ----------------
__global__ __launch_bounds__(256)
void poolnorm2(const float* __restrict__ X, const float* __restrict__ na,
               const float* __restrict__ nb, float* __restrict__ pooled) {
  __shared__ float red[4][64];
  const int b = blockIdx.x, d0 = blockIdx.y * 64;
  const int dl = threadIdx.x & 63, g = threadIdx.x >> 6;
  const float* p = X + (size_t)b * (PATCHES * DIM) + d0 + dl;
  float s = 0.f;
  for (int i = g; i < PATCHES; i += 4) s += p[(size_t)i * DIM];
  red[g][dl] = s;
  __syncthreads();
  if (threadIdx.x < 64) {
    float tot = red[0][dl] + red[1][dl] + red[2][dl] + red[3][dl];
    int d = d0 + dl;
    pooled[b * DIM + d] = (tot * (1.0f / 196.0f)) * na[d] + nb[d];
  }
}

// ---------------- head: out[b,n] = pooled[b,:] . Whq[n,:] + hb[n] (fp32) ----------------
__global__ __launch_bounds__(256)
void head_k2(const float* __restrict__ pooled, const float* __restrict__ Whq,
             const float* __restrict__ hb, float* __restrict__ out) {
  __shared__ float pl[DIM];
  const int b = blockIdx.x, t = threadIdx.x;
  if (t < 192) {
    pl[t] = pooled[b * DIM + t];
    pl[t + 192] = pooled[b * DIM + t + 192];
  }
  __syncthreads();
  const int n = blockIdx.y * 64 + (t >> 2);
  if (n >= 1000) return;
  const int qofs = (t & 3) * 96;
  const float4* w = (const float4*)(Whq + (size_t)n * DIM + qofs);
  const float* p = pl + qofs;
  float s = 0.f;
#pragma unroll 6
  for (int i = 0; i < 24; ++i) {
    float4 wv = w[i];
    s += p[4 * i] * wv.x + p[4 * i + 1] * wv.y + p[4 * i + 2] * wv.z + p[4 * i + 3] * wv.w;
  }
  s += __shfl_down(s, 2, 4);
  s += __shfl_down(s, 1, 4);
  if ((t & 3) == 0) out[b * 1000 + n] = s + hb[n];
}

extern "C" void kernel_launch(void* const* d_in, const int* in_sizes, int n_in,
                              void* d_out, int out_size, void* d_ws, size_t ws_size,
                              hipStream_t stream) {
  const float* x       = (const float*)d_in[0];
  const float* conv_w  = (const float*)d_in[1];
  const float* conv_b  = (const float*)d_in[2];
  const float* norm1_a = (const float*)d_in[3];
  const float* norm1_b = (const float*)d_in[4];
  const float* attn_w  = (const float*)d_in[5];
  const float* attn_b  = (const float*)d_in[6];
  const float* gamma1  = (const float*)d_in[7];
  const float* norm2_a = (const float*)d_in[8];
  const float* norm2_b = (const float*)d_in[9];
  const float* mlp_w1  = (const float*)d_in[10];
  const float* mlp_b1  = (const float*)d_in[11];
  const float* mlp_w2  = (const float*)d_in[12];
  const float* mlp_b2  = (const float*)d_in[13];
  const float* gamma2  = (const float*)d_in[14];
  const float* norm_a  = (const float*)d_in[15];
  const float* norm_b  = (const float*)d_in[16];
  const float* head_w  = (const float*)d_in[17];
  const float* head_b  = (const float*)d_in[18];
  (void)in_sizes; (void)n_in; (void)out_size; (void)ws_size;

  char* ws = (char*)d_ws;
  size_t off = 0;
  auto alloc = [&](size_t bytes) {
    off = (off + 255) & ~(size_t)255;
    void* p = ws + off;
    off += bytes;
    return p;
  };
  unsigned* scales = (unsigned*)alloc(74 * 4);
  short* conv_wq = (short*)alloc((size_t)DIM * 768 * 2);
  uchar* attn_wq = (uchar*)alloc((size_t)NBLK * PATCHES * NPAD);
  uchar* w1q     = (uchar*)alloc((size_t)NBLK * HID * DIM);
  uchar* w2q     = (uchar*)alloc((size_t)NBLK * DIM * HID);
  float* headq   = (float*)alloc((size_t)1000 * DIM * 4);
  float* X       = (float*)alloc((size_t)XELEMS * 4);
  uchar* Yt      = (uchar*)alloc((size_t)BDCOLS * NPAD);
  uchar* Y2      = (uchar*)alloc((size_t)XELEMS);
  uchar* H       = (uchar*)alloc((size_t)XROWS * HID);
  float* pooled  = (float*)alloc((size_t)64 * DIM * 4);
  short* Xa = (short*)H;  // alias: im2col [12544][768] bf16 (19.3MB), dead before H written

  hipMemsetAsync(scales, 0, 74 * 4, stream);
  hipMemsetAsync(Yt, 0, (size_t)BDCOLS * NPAD, stream);  // zero K-pad cols (p>=196)
  // scale slots: [0]=conv, [1]=head, [2..25]=attn, [26..49]=w1, [50..73]=w2
  absmax_v4<<<32, 256, 0, stream>>>(conv_w, DIM * 768 / 4, 32, scales + 0);
  absmax_v4<<<32, 256, 0, stream>>>(head_w, 1000 * DIM / 4, 32, scales + 1);
  absmax_v4<<<NBLK * 8, 256, 0, stream>>>(attn_w, PATCHES * PATCHES / 4, 8, scales + 2);
  absmax_v4<<<NBLK * 64, 256, 0, stream>>>(mlp_w1, HID * DIM / 4, 64, scales + 26);
  absmax_v4<<<NBLK * 64, 256, 0, stream>>>(mlp_w2, DIM * HID / 4, 64, scales + 50);

  quant_w<<<(DIM * 768 + 255) / 256, 256, 0, stream>>>(conv_w, conv_wq, scales + 0, DIM * 768, DIM * 768);
  quant_fp8<<<(NBLK * HID * DIM / 4 + 255) / 256, 256, 0, stream>>>(
      mlp_w1, (unsigned*)w1q, scales + 26, HID * DIM, NBLK * HID * DIM / 4);
  quant_fp8<<<(NBLK * HID * DIM / 4 + 255) / 256, 256, 0, stream>>>(
      mlp_w2, (unsigned*)w2q, scales + 50, DIM * HID, NBLK * DIM * HID / 4);
  quant_attn_fp8<<<(NBLK * PATCHES * NPAD / 4 + 255) / 256, 256, 0, stream>>>(
      attn_w, (unsigned*)attn_wq, scales + 2);
  quant_head_v4<<<(1000 * DIM / 4 + 255) / 256, 256, 0, stream>>>(head_w, headq, scales + 1);

  im2col_k<<<(XROWS * 768 / 4) / 256, 256, 0, stream>>>(x, Xa);
  gemm_conv<<<dim3(3, 196), 256, 0, stream>>>(Xa, conv_wq, X, conv_b, norm1_a, norm1_b, Yt);

  for (int blk = 0; blk < NBLK; ++blk) {
    gemm8<1><<<dim3(BDCOLS / 128, 4), 256, 0, stream>>>(
        attn_wq + (size_t)blk * PATCHES * NPAD, NPAD, PATCHES, Yt, NPAD, NPAD,
        X, Y2, attn_b + blk * PATCHES, gamma1 + blk * DIM,
        norm2_a + blk * DIM, norm2_b + blk * DIM, nullptr, nullptr, nullptr);
    gemm8<2><<<dim3(HID / 128, XROWS / 64), 256, 0, stream>>>(
        Y2, DIM, XROWS, w1q + (size_t)blk * HID * DIM, DIM, DIM,
        nullptr, H, mlp_b1 + blk * HID, nullptr, nullptr, nullptr,
        nullptr, nullptr, nullptr);
    const bool last = (blk == NBLK - 1);
    gemm8<3><<<dim3(DIM / 128, XROWS / 64), 256, 0, stream>>>(
        H, HID, XROWS, w2q + (size_t)blk * DIM * HID, HID, HID,
        X, nullptr, mlp_b2 + blk * DIM, gamma2 + blk * DIM, nullptr, nullptr,
        last ? nullptr : norm1_a + (blk + 1) * DIM,
        last ? nullptr : norm1_b + (blk + 1) * DIM,
        last ? nullptr : Yt);
  }

  poolnorm2<<<dim3(64, 6), 256, 0, stream>>>(X, norm_a, norm_b, pooled);
  head_k2<<<dim3(64, 16), 256, 0, stream>>>(pooled, headq, head_b, (float*)d_out);
}

// Round 18
// 1943.918 us; speedup vs baseline: 1.0565x; 1.0565x over previous
//
#include <hip/hip_runtime.h>

#define DIM 384
#define PATCHES 196
#define HID 1536
#define NBLK 24
#define NPAD 256                    // K-padded patch count for attn GEMM (fp8 bytes)
#define XROWS (64 * PATCHES)        // 12544
#define BDCOLS (64 * DIM)           // 24576
#define XELEMS (XROWS * DIM)        // 4816896
#define ESTRIDE 132                 // epilogue LDS stage row stride (floats)

typedef __attribute__((ext_vector_type(8))) short s8v;
typedef __attribute__((ext_vector_type(4))) float f4v;
typedef __attribute__((ext_vector_type(4))) int i32x4;
typedef __attribute__((ext_vector_type(8))) int i32x8;
typedef unsigned char uchar;

__device__ __forceinline__ short f2bf(float f) {
  unsigned u = __float_as_uint(f);
  u += 0x7FFFu + ((u >> 16) & 1u);   // RNE f32 -> bf16
  return (short)(u >> 16);
}

__device__ __forceinline__ float gelu_f(float x) {
  float u2 = 1.5957691216f * (x + 0.044715f * x * x * x);
  return x / (1.0f + __expf(-u2));
}

__device__ __forceinline__ unsigned pk4_fp8(float a, float b, float c, float d) {
  int lo = __builtin_amdgcn_cvt_pk_fp8_f32(a, b, 0, false);
  int full = __builtin_amdgcn_cvt_pk_fp8_f32(c, d, lo, true);
  return (unsigned)full;
}
__device__ __forceinline__ uchar fp8_1(float a) {
  return (uchar)(__builtin_amdgcn_cvt_pk_fp8_f32(a, a, 0, false) & 0xff);
}

__device__ __forceinline__ void gload_lds16(const void* g, void* l) {
  __builtin_amdgcn_global_load_lds((const __attribute__((address_space(1))) void*)g,
                                   (__attribute__((address_space(3))) void*)l, 16, 0, 0);
}

// ---------------- absmax (per-tensor, float4) ----------------
__global__ __launch_bounds__(256)
void absmax_v4(const float* __restrict__ src, int f4per, int blocks_per,
               unsigned* __restrict__ out) {
  int tens = blockIdx.x / blocks_per;
  int sl = blockIdx.x - tens * blocks_per;
  const float4* p = (const float4*)(src + (size_t)tens * f4per * 4);
  float m = 0.f;
  for (int i = sl * 256 + threadIdx.x; i < f4per; i += blocks_per * 256) {
    float4 v = p[i];
    m = fmaxf(m, fmaxf(fmaxf(fabsf(v.x), fabsf(v.y)), fmaxf(fabsf(v.z), fabsf(v.w))));
  }
  __shared__ float red[256];
  red[threadIdx.x] = m;
  __syncthreads();
  for (int s = 128; s > 0; s >>= 1) {
    if ((int)threadIdx.x < s) red[threadIdx.x] = fmaxf(red[threadIdx.x], red[threadIdx.x + s]);
    __syncthreads();
  }
  if (threadIdx.x == 0) atomicMax(out + tens, __float_as_uint(red[0]));
}

// ---------------- quantize conv weights (fq bit-exact, bf16 store) ----------------
__global__ __launch_bounds__(256)
void quant_w(const float* __restrict__ w, short* __restrict__ q,
             const unsigned* __restrict__ sc, int per, int total) {
  int i = blockIdx.x * 256 + threadIdx.x;
  if (i >= total) return;
  int tens = i / per;
  float s = __uint_as_float(sc[tens]) / 127.0f + 1e-8f;
  float v = rintf(w[i] / s);
  v = fminf(fmaxf(v, -128.0f), 127.0f) * s;
  q[i] = f2bf(v);
}

// ---------------- quantize mlp weights (fq then fp8 e4m3, x4 vector) ----------------
__global__ __launch_bounds__(256)
void quant_fp8(const float* __restrict__ w, unsigned* __restrict__ q,
               const unsigned* __restrict__ sc, int per, int total4) {
  int i = blockIdx.x * 256 + threadIdx.x;
  if (i >= total4) return;
  int e = i << 2;
  int tens = e / per;
  float s = __uint_as_float(sc[tens]) / 127.0f + 1e-8f;
  float4 w4 = *(const float4*)(w + e);
  float a = fminf(fmaxf(rintf(w4.x / s), -128.0f), 127.0f) * s;
  float b = fminf(fmaxf(rintf(w4.y / s), -128.0f), 127.0f) * s;
  float c = fminf(fmaxf(rintf(w4.z / s), -128.0f), 127.0f) * s;
  float d = fminf(fmaxf(rintf(w4.w / s), -128.0f), 127.0f) * s;
  q[i] = pk4_fp8(a, b, c, d);
}

__global__ __launch_bounds__(256)
void quant_attn_fp8(const float* __restrict__ w, unsigned* __restrict__ q,
                    const unsigned* __restrict__ sc) {
  int i = blockIdx.x * 256 + threadIdx.x;       // over 24*196*256/4
  if (i >= NBLK * PATCHES * NPAD / 4) return;
  int e = i << 2;
  int col = e & (NPAD - 1);
  int rt = e >> 8;
  int row = rt % PATCHES;
  int tens = rt / PATCHES;
  float s = __uint_as_float(sc[tens]) / 127.0f + 1e-8f;
  const float* wr = w + (size_t)tens * PATCHES * PATCHES + (size_t)row * PATCHES;
  float v[4];
#pragma unroll
  for (int k = 0; k < 4; ++k) {
    int c = col + k;
    v[k] = (c < PATCHES) ? fminf(fmaxf(rintf(wr[c] / s), -128.0f), 127.0f) * s : 0.f;
  }
  q[i] = pk4_fp8(v[0], v[1], v[2], v[3]);
}

__global__ __launch_bounds__(256)
void quant_head_v4(const float* __restrict__ w, float* __restrict__ q,
                   const unsigned* __restrict__ sc) {
  int i = blockIdx.x * 256 + threadIdx.x;
  if (i >= 1000 * DIM / 4) return;
  float s = __uint_as_float(sc[0]) / 127.0f + 1e-8f;
  float4 w4 = *(const float4*)(w + (i << 2));
  float4 o;
  o.x = fminf(fmaxf(rintf(w4.x / s), -128.0f), 127.0f) * s;
  o.y = fminf(fmaxf(rintf(w4.y / s), -128.0f), 127.0f) * s;
  o.z = fminf(fmaxf(rintf(w4.z / s), -128.0f), 127.0f) * s;
  o.w = fminf(fmaxf(rintf(w4.w / s), -128.0f), 127.0f) * s;
  *(float4*)(q + (i << 2)) = o;
}

// ---------------- im2col + bf16 cast (stride-16 16x16 patches: no overlap) ----------------
__global__ __launch_bounds__(256)
void im2col_k(const float* __restrict__ x, short* __restrict__ Xa) {
  int idx = blockIdx.x * 256 + threadIdx.x;     // each handles 4 elems
  if (idx >= XROWS * 768 / 4) return;
  int e = idx << 2;
  int r = e / 768, k = e - r * 768;
  int b = r / PATCHES, p = r - b * PATCHES;
  int c = k >> 8, rem = k & 255, ii = rem >> 4, j = rem & 15;
  int ph = p / 14, pw = p - ph * 14;
  const float4 v = *(const float4*)(x + (b * 3 + c) * 50176 + (ph * 16 + ii) * 224 + pw * 16 + j);
  short2* o = (short2*)(Xa + e);
  o[0] = make_short2(f2bf(v.x), f2bf(v.y));
  o[1] = make_short2(f2bf(v.z), f2bf(v.w));
}

// ---------------- conv GEMM (bf16): X = Xa * Wc^T + b; fused norm1 -> Yt (fp8) ------
__global__ __launch_bounds__(256)
void gemm_conv(const short* __restrict__ A, const short* __restrict__ B,
               float* __restrict__ Xres, const float* __restrict__ bias,
               const float* __restrict__ n1a, const float* __restrict__ n1b,
               uchar* __restrict__ Yt) {
  constexpr int TILE_SHORTS = 192 * 64;
  __shared__ char smem[2 * TILE_SHORTS * 2];     // 49152 B
  short* buf0 = (short*)smem;
  float* S = (float*)smem;
  const int lda = 768, K = 768;

  const int t = threadIdx.x;
  const int lane = t & 63;
  const int wid = t >> 6;
  const int wr = wid >> 1, wc = wid & 1;

  const int gx = gridDim.x;
  const int nwg = gx * gridDim.y;
  const int orig = blockIdx.y * gx + blockIdx.x;
  const int q = nwg >> 3, rm = nwg & 7;
  const int xc = orig & 7, jj = orig >> 3;
  const int wg = (xc < rm ? xc * (q + 1) : rm * (q + 1) + (xc - rm) * q) + jj;
  const int bx = wg % gx, by = wg / gx;
  const int m0 = by * 64, n0 = bx * 128;

  f4v acc[2][4];
#pragma unroll
  for (int m = 0; m < 2; ++m)
#pragma unroll
    for (int n = 0; n < 4; ++n) acc[m][n] = (f4v){0.f, 0.f, 0.f, 0.f};

  const int srow = t >> 3;
  const int scol = ((t & 7) ^ (srow & 7)) << 3;  // shorts
  const short* ga[2];
#pragma unroll
  for (int h = 0; h < 2; ++h) ga[h] = A + (size_t)(m0 + h * 32 + srow) * lda + scol;
  const short* gb[4];
#pragma unroll
  for (int j = 0; j < 4; ++j) gb[j] = B + (size_t)(n0 + j * 32 + srow) * lda + scol;
  short* ldst = buf0 + (t & ~63) * 8;

  auto stage = [&](int slot, int kt) {
    const int koff = kt << 6;
    const int boff = slot * TILE_SHORTS;
    gload_lds16(ga[0] + koff, ldst + boff);
    gload_lds16(ga[1] + koff, ldst + boff + 2048);
#pragma unroll
    for (int j = 0; j < 4; ++j)
      gload_lds16(gb[j] + koff, ldst + boff + 4096 + j * 2048);
  };

  const int l15 = lane & 15, lk = lane >> 4, l7 = lane & 7;
  int paoff[2], pboff[2];
#pragma unroll
  for (int ks = 0; ks < 2; ++ks) {
    const int cgx = ((ks << 2) + lk) ^ l7;
    paoff[ks] = (wr * 32 + l15) * 64 + (cgx << 3);
    pboff[ks] = 4096 + (wc * 64 + l15) * 64 + (cgx << 3);
  }

  const int nk = K >> 6;
  stage(0, 0);
  asm volatile("s_waitcnt vmcnt(0)" ::: "memory");
  __builtin_amdgcn_s_barrier();
  for (int kt = 0; kt < nk; ++kt) {
    const int cur = kt & 1;
    if (kt + 1 < nk) stage(cur ^ 1, kt + 1);
    const short* base = buf0 + cur * TILE_SHORTS;
    s8v af[2][2], bfr[4][2];
#pragma unroll
    for (int m = 0; m < 2; ++m)
#pragma unroll
      for (int ks = 0; ks < 2; ++ks) af[m][ks] = *(const s8v*)(base + paoff[ks] + m * 1024);
#pragma unroll
    for (int n = 0; n < 4; ++n)
#pragma unroll
      for (int ks = 0; ks < 2; ++ks) bfr[n][ks] = *(const s8v*)(base + pboff[ks] + n * 1024);
    asm volatile("s_waitcnt lgkmcnt(0)" ::: "memory");
    __builtin_amdgcn_sched_barrier(0);
    __builtin_amdgcn_s_setprio(1);
#pragma unroll
    for (int m = 0; m < 2; ++m)
#pragma unroll
      for (int n = 0; n < 4; ++n)
#pragma unroll
        for (int ks = 0; ks < 2; ++ks)
          acc[m][n] = __builtin_amdgcn_mfma_f32_16x16x32_bf16(af[m][ks], bfr[n][ks], acc[m][n], 0, 0, 0);
    __builtin_amdgcn_s_setprio(0);
    if (kt + 1 < nk) {
      asm volatile("s_waitcnt vmcnt(0)" ::: "memory");
      __builtin_amdgcn_s_barrier();
    }
  }

  // epilogue via LDS transpose
  const int cb = (wc << 6) + l15;
  const int rl = t >> 3;
  const int c0 = (t & 7) << 4;
#pragma unroll
  for (int m = 0; m < 2; ++m) {
    __syncthreads();
#pragma unroll
    for (int n = 0; n < 4; ++n) {
      int c = cb + n * 16;
#pragma unroll
      for (int j = 0; j < 4; ++j)
        S[((wr << 4) + (lk << 2) + j) * ESTRIDE + c] = acc[m][n][j];
    }
    __syncthreads();
    const int r = m0 + (rl >> 4) * 32 + m * 16 + (rl & 15);
    const int colg = n0 + c0;
    float xn[16];
#pragma unroll
    for (int i = 0; i < 4; ++i) {
      float4 q4 = *(const float4*)(S + rl * ESTRIDE + c0 + i * 4);
      float4 b4 = *(const float4*)(bias + colg + i * 4);
      float4 o4 = make_float4(q4.x + b4.x, q4.y + b4.y, q4.z + b4.z, q4.w + b4.w);
      *(float4*)(Xres + (size_t)r * DIM + colg + i * 4) = o4;
      xn[4 * i] = o4.x; xn[4 * i + 1] = o4.y; xn[4 * i + 2] = o4.z; xn[4 * i + 3] = o4.w;
    }
    int bb = r / PATCHES, p = r - bb * PATCHES;
    uchar* yrow = Yt + ((size_t)(bb * DIM + colg)) * NPAD + p;
#pragma unroll
    for (int i = 0; i < 4; ++i) {
      float4 a4 = *(const float4*)(n1a + colg + i * 4);
      float4 b4 = *(const float4*)(n1b + colg + i * 4);
      yrow[(4 * i + 0) * NPAD] = fp8_1(xn[4 * i] * a4.x + b4.x);
      yrow[(4 * i + 1) * NPAD] = fp8_1(xn[4 * i + 1] * a4.y + b4.y);
      yrow[(4 * i + 2) * NPAD] = fp8_1(xn[4 * i + 2] * a4.z + b4.z);
      yrow[(4 * i + 3) * NPAD] = fp8_1(xn[4 * i + 3] * a4.w + b4.w);
    }
  }
}

// ---------------- FP8 GEMM C = A * B^T, tile 64x128, BK=128, 2-buffer, MX MFMA -----
// One mfma_scale_f32_16x16x128_f8f6f4 (unit E8M0 scales = 0x7F) per K-step per (m,n)
// — 2x matrix rate vs 16x16x32 fp8, 4x fewer MFMA insts, half the ds_reads.
// Lane fragment: row = lane&15, k-bytes [32*(lane>>4), +32) = swizzled chunks
// (2*lk)^(row&7), (2*lk+1)^(row&7). Same LDS layout/staging as the r7 kernel.
// EPI 1: attn -> xn = X + g1*(acc + bias[r]); X = xn; Y2fp8 = xn*n2a+n2b
// EPI 2: mlp1 -> H = fp8(gelu(acc + bias[c]))
// EPI 3: mlp2 -> X += g2*(acc + bias[c]); fused norm1 -> Yt fp8 (next layer)
template <int EPI>
__global__ __launch_bounds__(256)
void gemm8(const uchar* __restrict__ A, int lda8, int Mlim,
           const uchar* __restrict__ B, int ldb8, int K,
           float* __restrict__ Xres, uchar* __restrict__ OutB8,
           const float* __restrict__ bias, const float* __restrict__ gamma,
           const float* __restrict__ n2a, const float* __restrict__ n2b,
           const float* __restrict__ n1a, const float* __restrict__ n1b,
           uchar* __restrict__ Yt) {
  constexpr int TILE_BYTES = 192 * 128;          // A 64x128B + B 128x128B = 24576
  __shared__ char smem[2 * TILE_BYTES];          // 49152 B
  char* buf0 = smem;
  float* S = (float*)smem;

  const int t = threadIdx.x;
  const int lane = t & 63;
  const int wid = t >> 6;
  const int wr = wid >> 1, wc = wid & 1;

  const int gx = gridDim.x;
  const int nwg = gx * gridDim.y;
  const int orig = blockIdx.y * gx + blockIdx.x;
  const int q = nwg >> 3, rm = nwg & 7;
  const int xc = orig & 7, jj = orig >> 3;
  const int wg = (xc < rm ? xc * (q + 1) : rm * (q + 1) + (xc - rm) * q) + jj;
  const int bx = wg % gx, by = wg / gx;
  const int m0 = by * 64, n0 = bx * 128;

  f4v acc[2][4];
#pragma unroll
  for (int m = 0; m < 2; ++m)
#pragma unroll
    for (int n = 0; n < 4; ++n) acc[m][n] = (f4v){0.f, 0.f, 0.f, 0.f};

  // staging: thread t -> (row = pass*32 + (t>>3), chunk_pos = t&7); src chunk pre-swizzled
  const int srow = t >> 3;
  const int scolB = (((t & 7) ^ (srow & 7)) << 4);   // bytes
  const uchar* ga[2];
#pragma unroll
  for (int h = 0; h < 2; ++h) {
    int r = m0 + h * 32 + srow;
    if (r >= Mlim) r = Mlim - 1;
    ga[h] = A + (size_t)r * lda8 + scolB;
  }
  const uchar* gb[4];
#pragma unroll
  for (int j = 0; j < 4; ++j)
    gb[j] = B + (size_t)(n0 + j * 32 + srow) * ldb8 + scolB;
  char* ldst = buf0 + (t & ~63) * 16;              // wave base; HW adds lane*16B

  auto stage = [&](int slot, int kt) {
    const int koff = kt << 7;                      // 128 B per K-tile
    const int boff = slot * TILE_BYTES;
    gload_lds16(ga[0] + koff, ldst + boff);
    gload_lds16(ga[1] + koff, ldst + boff + 4096);
#pragma unroll
    for (int j = 0; j < 4; ++j)
      gload_lds16(gb[j] + koff, ldst + boff + 8192 + j * 4096);
  };

  const int l15 = lane & 15, lk = lane >> 4, l7 = lane & 7;
  // MX fragment: two 16B chunks per operand, global chunks 2*lk, 2*lk+1
  const int cA0 = (((lk << 1) | 0) ^ l7) << 4;
  const int cA1 = (((lk << 1) | 1) ^ l7) << 4;
  int arow[2], brow[4];
#pragma unroll
  for (int m = 0; m < 2; ++m) arow[m] = (wr * 32 + m * 16 + l15) << 7;
#pragma unroll
  for (int n = 0; n < 4; ++n) brow[n] = 8192 + ((wc * 64 + n * 16 + l15) << 7);

  const int nk = K >> 7;
  stage(0, 0);
  asm volatile("s_waitcnt vmcnt(0)" ::: "memory");
  __builtin_amdgcn_s_barrier();
  for (int kt = 0; kt < nk; ++kt) {
    const int cur = kt & 1;
    if (kt + 1 < nk) stage(cur ^ 1, kt + 1);
    const char* base = buf0 + cur * TILE_BYTES;
    i32x8 af[2], bfr[4];
#pragma unroll
    for (int m = 0; m < 2; ++m) {
      i32x4 lo = *(const i32x4*)(base + arow[m] + cA0);
      i32x4 hi = *(const i32x4*)(base + arow[m] + cA1);
      af[m][0] = lo[0]; af[m][1] = lo[1]; af[m][2] = lo[2]; af[m][3] = lo[3];
      af[m][4] = hi[0]; af[m][5] = hi[1]; af[m][6] = hi[2]; af[m][7] = hi[3];
    }
#pragma unroll
    for (int n = 0; n < 4; ++n) {
      i32x4 lo = *(const i32x4*)(base + brow[n] + cA0);
      i32x4 hi = *(const i32x4*)(base + brow[n] + cA1);
      bfr[n][0] = lo[0]; bfr[n][1] = lo[1]; bfr[n][2] = lo[2]; bfr[n][3] = lo[3];
      bfr[n][4] = hi[0]; bfr[n][5] = hi[1]; bfr[n][6] = hi[2]; bfr[n][7] = hi[3];
    }
    asm volatile("s_waitcnt lgkmcnt(0)" ::: "memory");
    __builtin_amdgcn_sched_barrier(0);
    __builtin_amdgcn_s_setprio(1);
#pragma unroll
    for (int m = 0; m < 2; ++m)
#pragma unroll
      for (int n = 0; n < 4; ++n)
        acc[m][n] = __builtin_amdgcn_mfma_scale_f32_16x16x128_f8f6f4(
            af[m], bfr[n], acc[m][n], 0, 0, 0, 0x7F7F7F7F, 0, 0x7F7F7F7F);
    __builtin_amdgcn_s_setprio(0);
    if (kt + 1 < nk) {
      asm volatile("s_waitcnt vmcnt(0)" ::: "memory");
      __builtin_amdgcn_s_barrier();
    }
  }

  // ---------------- epilogue via LDS transpose ----------------
  const int cb = (wc << 6) + l15;
  const int rl = t >> 3;
  const int c0 = (t & 7) << 4;
#pragma unroll
  for (int m = 0; m < 2; ++m) {
    __syncthreads();
#pragma unroll
    for (int n = 0; n < 4; ++n) {
      int c = cb + n * 16;
#pragma unroll
      for (int j = 0; j < 4; ++j)
        S[((wr << 4) + (lk << 2) + j) * ESTRIDE + c] = acc[m][n][j];
    }
    __syncthreads();
    const int r = m0 + (rl >> 4) * 32 + m * 16 + (rl & 15);
    const int colg = n0 + c0;
    float v[16];
#pragma unroll
    for (int i = 0; i < 4; ++i) {
      float4 q4 = *(const float4*)(S + rl * ESTRIDE + c0 + i * 4);
      v[4 * i] = q4.x; v[4 * i + 1] = q4.y; v[4 * i + 2] = q4.z; v[4 * i + 3] = q4.w;
    }
    if (EPI == 1) {
      if (r < Mlim) {
        const int b = colg / DIM, d0 = colg - b * DIM;
        const float br = bias[r];
        const size_t base2 = (size_t)b * (PATCHES * DIM) + (size_t)r * DIM + d0;
        float xn[16];
#pragma unroll
        for (int i = 0; i < 4; ++i) {
          float4 g4 = *(const float4*)(gamma + d0 + i * 4);
          float4 x4 = *(const float4*)(Xres + base2 + i * 4);
          x4.x += g4.x * (v[4 * i] + br);
          x4.y += g4.y * (v[4 * i + 1] + br);
          x4.z += g4.z * (v[4 * i + 2] + br);
          x4.w += g4.w * (v[4 * i + 3] + br);
          *(float4*)(Xres + base2 + i * 4) = x4;
          xn[4 * i] = x4.x; xn[4 * i + 1] = x4.y; xn[4 * i + 2] = x4.z; xn[4 * i + 3] = x4.w;
        }
        unsigned o[4];
#pragma unroll
        for (int i = 0; i < 4; ++i) {
          float4 a4 = *(const float4*)(n2a + d0 + i * 4);
          float4 b4 = *(const float4*)(n2b + d0 + i * 4);
          o[i] = pk4_fp8(xn[4 * i] * a4.x + b4.x, xn[4 * i + 1] * a4.y + b4.y,
                         xn[4 * i + 2] * a4.z + b4.z, xn[4 * i + 3] * a4.w + b4.w);
        }
        *(uint4*)(OutB8 + base2) = make_uint4(o[0], o[1], o[2], o[3]);
      }
    } else if (EPI == 2) {
      unsigned o[4];
#pragma unroll
      for (int i = 0; i < 4; ++i) {
        float g0 = gelu_f(v[4 * i] + bias[colg + 4 * i]);
        float g1 = gelu_f(v[4 * i + 1] + bias[colg + 4 * i + 1]);
        float g2 = gelu_f(v[4 * i + 2] + bias[colg + 4 * i + 2]);
        float g3 = gelu_f(v[4 * i + 3] + bias[colg + 4 * i + 3]);
        o[i] = pk4_fp8(g0, g1, g2, g3);
      }
      *(uint4*)(OutB8 + (size_t)r * HID + colg) = make_uint4(o[0], o[1], o[2], o[3]);
    } else {  // EPI == 3
      float xn[16];
#pragma unroll
      for (int i = 0; i < 4; ++i) {
        float4 b4 = *(const float4*)(bias + colg + i * 4);
        float4 g4 = *(const float4*)(gamma + colg + i * 4);
        float4 x4 = *(const float4*)(Xres + (size_t)r * DIM + colg + i * 4);
        x4.x += g4.x * (v[4 * i] + b4.x);
        x4.y += g4.y * (v[4 * i + 1] + b4.y);
        x4.z += g4.z * (v[4 * i + 2] + b4.z);
        x4.w += g4.w * (v[4 * i + 3] + b4.w);
        *(float4*)(Xres + (size_t)r * DIM + colg + i * 4) = x4;
        xn[4 * i] = x4.x; xn[4 * i + 1] = x4.y; xn[4 * i + 2] = x4.z; xn[4 * i + 3] = x4.w;
      }
      if (Yt != nullptr) {
        int bb = r / PATCHES, p = r - bb * PATCHES;
        uchar* yrow = Yt + ((size_t)(bb * DIM + colg)) * NPAD + p;
#pragma unroll
        for (int i = 0; i < 4; ++i) {
          float4 a4 = *(const float4*)(n1a + colg + i * 4);
          float4 b4 = *(const float4*)(n1b + colg + i * 4);
          yrow[(4 * i + 0) * NPAD] = fp8_1(xn[4 * i] * a4.x + b4.x);
          yrow[(4 * i + 1) * NPAD] = fp8_1(xn[4 * i + 1] * a4.y + b4.y);
          yrow[(4 * i + 2) * NPAD] = fp8_1(xn[4 * i + 2] * a4.z + b4.z);
          yrow[(4 * i + 3) * NPAD] = fp8_1(xn[4 * i + 3] * a4.w + b4.w);
        }
      }
    }
  }
}

// ---------------- final affine norm + mean pool (parallelized) ----------------
__global__ __launch_bounds__(256)
void poolnorm2(const float* __restrict__ X, const float* __restrict__ na,
               const float* __restrict__ nb, float* __restrict__ pooled) {
  __shared__ float red[4][64];
  const int b = blockIdx.x, d0 = blockIdx.y * 64;
  const int dl = threadIdx.x & 63, g = threadIdx.x >> 6;
  const float* p = X + (size_t)b * (PATCHES * DIM) + d0 + dl;
  float s = 0.f;
  for (int i = g; i < PATCHES; i += 4) s += p[(size_t)i * DIM];
  red[g][dl] = s;
  __syncthreads();
  if (threadIdx.x < 64) {
    float tot = red[0][dl] + red[1][dl] + red[2][dl] + red[3][dl];
    int d = d0 + dl;
    pooled[b * DIM + d] = (tot * (1.0f / 196.0f)) * na[d] + nb[d];
  }
}

// ---------------- head: out[b,n] = pooled[b,:] . Whq[n,:] + hb[n] (fp32) ----------------
__global__ __launch_bounds__(256)
void head_k2(const float* __restrict__ pooled, const float* __restrict__ Whq,
             const float* __restrict__ hb, float* __restrict__ out) {
  __shared__ float pl[DIM];
  const int b = blockIdx.x, t = threadIdx.x;
  if (t < 192) {
    pl[t] = pooled[b * DIM + t];
    pl[t + 192] = pooled[b * DIM + t + 192];
  }
  __syncthreads();
  const int n = blockIdx.y * 64 + (t >> 2);
  if (n >= 1000) return;
  const int qofs = (t & 3) * 96;
  const float4* w = (const float4*)(Whq + (size_t)n * DIM + qofs);
  const float* p = pl + qofs;
  float s = 0.f;
#pragma unroll 6
  for (int i = 0; i < 24; ++i) {
    float4 wv = w[i];
    s += p[4 * i] * wv.x + p[4 * i + 1] * wv.y + p[4 * i + 2] * wv.z + p[4 * i + 3] * wv.w;
  }
  s += __shfl_down(s, 2, 4);
  s += __shfl_down(s, 1, 4);
  if ((t & 3) == 0) out[b * 1000 + n] = s + hb[n];
}

extern "C" void kernel_launch(void* const* d_in, const int* in_sizes, int n_in,
                              void* d_out, int out_size, void* d_ws, size_t ws_size,
                              hipStream_t stream) {
  const float* x       = (const float*)d_in[0];
  const float* conv_w  = (const float*)d_in[1];
  const float* conv_b  = (const float*)d_in[2];
  const float* norm1_a = (const float*)d_in[3];
  const float* norm1_b = (const float*)d_in[4];
  const float* attn_w  = (const float*)d_in[5];
  const float* attn_b  = (const float*)d_in[6];
  const float* gamma1  = (const float*)d_in[7];
  const float* norm2_a = (const float*)d_in[8];
  const float* norm2_b = (const float*)d_in[9];
  const float* mlp_w1  = (const float*)d_in[10];
  const float* mlp_b1  = (const float*)d_in[11];
  const float* mlp_w2  = (const float*)d_in[12];
  const float* mlp_b2  = (const float*)d_in[13];
  const float* gamma2  = (const float*)d_in[14];
  const float* norm_a  = (const float*)d_in[15];
  const float* norm_b  = (const float*)d_in[16];
  const float* head_w  = (const float*)d_in[17];
  const float* head_b  = (const float*)d_in[18];
  (void)in_sizes; (void)n_in; (void)out_size; (void)ws_size;

  char* ws = (char*)d_ws;
  size_t off = 0;
  auto alloc = [&](size_t bytes) {
    off = (off + 255) & ~(size_t)255;
    void* p = ws + off;
    off += bytes;
    return p;
  };
  unsigned* scales = (unsigned*)alloc(74 * 4);
  short* conv_wq = (short*)alloc((size_t)DIM * 768 * 2);
  uchar* attn_wq = (uchar*)alloc((size_t)NBLK * PATCHES * NPAD);
  uchar* w1q     = (uchar*)alloc((size_t)NBLK * HID * DIM);
  uchar* w2q     = (uchar*)alloc((size_t)NBLK * DIM * HID);
  float* headq   = (float*)alloc((size_t)1000 * DIM * 4);
  float* X       = (float*)alloc((size_t)XELEMS * 4);
  uchar* Yt      = (uchar*)alloc((size_t)BDCOLS * NPAD);
  uchar* Y2      = (uchar*)alloc((size_t)XELEMS);
  uchar* H       = (uchar*)alloc((size_t)XROWS * HID);
  float* pooled  = (float*)alloc((size_t)64 * DIM * 4);
  short* Xa = (short*)H;  // alias: im2col [12544][768] bf16 (19.3MB), dead before H written

  hipMemsetAsync(scales, 0, 74 * 4, stream);
  hipMemsetAsync(Yt, 0, (size_t)BDCOLS * NPAD, stream);  // zero K-pad cols (p>=196)
  // scale slots: [0]=conv, [1]=head, [2..25]=attn, [26..49]=w1, [50..73]=w2
  absmax_v4<<<32, 256, 0, stream>>>(conv_w, DIM * 768 / 4, 32, scales + 0);
  absmax_v4<<<32, 256, 0, stream>>>(head_w, 1000 * DIM / 4, 32, scales + 1);
  absmax_v4<<<NBLK * 8, 256, 0, stream>>>(attn_w, PATCHES * PATCHES / 4, 8, scales + 2);
  absmax_v4<<<NBLK * 64, 256, 0, stream>>>(mlp_w1, HID * DIM / 4, 64, scales + 26);
  absmax_v4<<<NBLK * 64, 256, 0, stream>>>(mlp_w2, DIM * HID / 4, 64, scales + 50);

  quant_w<<<(DIM * 768 + 255) / 256, 256, 0, stream>>>(conv_w, conv_wq, scales + 0, DIM * 768, DIM * 768);
  quant_fp8<<<(NBLK * HID * DIM / 4 + 255) / 256, 256, 0, stream>>>(
      mlp_w1, (unsigned*)w1q, scales + 26, HID * DIM, NBLK * HID * DIM / 4);
  quant_fp8<<<(NBLK * HID * DIM / 4 + 255) / 256, 256, 0, stream>>>(
      mlp_w2, (unsigned*)w2q, scales + 50, DIM * HID, NBLK * DIM * HID / 4);
  quant_attn_fp8<<<(NBLK * PATCHES * NPAD / 4 + 255) / 256, 256, 0, stream>>>(
      attn_w, (unsigned*)attn_wq, scales + 2);
  quant_head_v4<<<(1000 * DIM / 4 + 255) / 256, 256, 0, stream>>>(head_w, headq, scales + 1);

  im2col_k<<<(XROWS * 768 / 4) / 256, 256, 0, stream>>>(x, Xa);
  gemm_conv<<<dim3(3, 196), 256, 0, stream>>>(Xa, conv_wq, X, conv_b, norm1_a, norm1_b, Yt);

  for (int blk = 0; blk < NBLK; ++blk) {
    gemm8<1><<<dim3(BDCOLS / 128, 4), 256, 0, stream>>>(
        attn_wq + (size_t)blk * PATCHES * NPAD, NPAD, PATCHES, Yt, NPAD, NPAD,
        X, Y2, attn_b + blk * PATCHES, gamma1 + blk * DIM,
        norm2_a + blk * DIM, norm2_b + blk * DIM, nullptr, nullptr, nullptr);
    gemm8<2><<<dim3(HID / 128, XROWS / 64), 256, 0, stream>>>(
        Y2, DIM, XROWS, w1q + (size_t)blk * HID * DIM, DIM, DIM,
        nullptr, H, mlp_b1 + blk * HID, nullptr, nullptr, nullptr,
        nullptr, nullptr, nullptr);
    const bool last = (blk == NBLK - 1);
    gemm8<3><<<dim3(DIM / 128, XROWS / 64), 256, 0, stream>>>(
        H, HID, XROWS, w2q + (size_t)blk * DIM * HID, HID, HID,
        X, nullptr, mlp_b2 + blk * DIM, gamma2 + blk * DIM, nullptr, nullptr,
        last ? nullptr : norm1_a + (blk + 1) * DIM,
        last ? nullptr : norm1_b + (blk + 1) * DIM,
        last ? nullptr : Yt);
  }

  poolnorm2<<<dim3(64, 6), 256, 0, stream>>>(X, norm_a, norm_b, pooled);
  head_k2<<<dim3(64, 16), 256, 0, stream>>>(pooled, headq, head_b, (float*)d_out);
}